// Round 7
// baseline (258.339 us; speedup 1.0000x reference)
//
#include <hip/hip_runtime.h>

#define EPS 1e-12f

constexpr int D       = 1024;  // feature dim
constexpr int K       = 16;    // centers per class
constexpr int NS      = 8;     // index-range slices per class
constexpr int LISTCAP = 1024;  // = SLICE (worst-case match count)

// ---------------------------------------------------------------------------
// Fused kernel. Block (c, sl) = (bid % C, bid / C):
//   A: stage class c's 16 center rows (64 KB) into LDS — deterministic
//      on-chip residency (round-6 lesson: register-resident centers got
//      silently demoted to per-sample cache reloads at VGPR=68).
//   B: scan labels[sl*SLICE ..), build LDS match list (shfl_up scan).
//   C: center norms from LDS; cinv -> per-lane registers.
//   D: sample loop — each wave independently processes PAIRS of samples:
//      2 x-rows in registers; one ds_read_b128 center fragment feeds 8 FMAs;
//      34-value butterfly; epilogue on lane 0; wave-private accumulator.
//      No barriers, no LDS traffic besides center reads.
//   E: 4-wave combine, one atomicAdd (out pre-zeroed by memset node).
// ---------------------------------------------------------------------------
__global__ __launch_bounds__(256, 2) void cosine_loss_fused(
    const float* __restrict__ x, const int* __restrict__ labels,
    const float* __restrict__ centers, float* __restrict__ out,
    int B, int C, float inv_B) {
    const int bid  = blockIdx.x;
    const int c    = bid % C;
    const int sl   = bid / C;
    const int tid  = threadIdx.x;
    const int w    = tid >> 6;
    const int lane = tid & 63;

    __shared__ float cLDS[K * D];      // 64 KB: class c's centers
    __shared__ int   list[LISTCAP];    // 4 KB: matching sample indices
    __shared__ int   wsumI[4];
    __shared__ float cinvLDS[K];
    __shared__ float wpart[4];

    const int SLICE = (B + NS - 1) / NS;       // 1024
    const int base  = sl * SLICE;
    const int lim   = min(SLICE, B - base);
    const int rpt   = (SLICE + 255) >> 8;      // 4

    // ---- A: stage centers -> LDS (coalesced float4, 16 iters/thread) ----
    {
        const float* csrc = centers + (size_t)c * (K * D);
#pragma unroll
        for (int i = 0; i < (K * D) / (256 * 4); ++i) {
            const int off = (i * 256 + tid) * 4;
            const float4 t = *reinterpret_cast<const float4*>(csrc + off);
            *reinterpret_cast<float4*>(&cLDS[off]) = t;
        }
    }

    // ---- B1: per-thread match mask over the slice (coalesced) ----
    int mmask = 0, cnt_t = 0;
    for (int r = 0; r < rpt; ++r) {
        const int idx = r * 256 + tid;
        if (idx < lim && labels[base + idx] == c) { mmask |= 1 << r; ++cnt_t; }
    }

    // ---- B2: intra-wave inclusive scan + cross-wave prefix ----
    int v = cnt_t;
#pragma unroll
    for (int off = 1; off < 64; off <<= 1) {
        const int u = __shfl_up(v, off, 64);
        if (lane >= off) v += u;
    }
    if (lane == 63) wsumI[w] = v;
    __syncthreads();   // covers staging writes + wsumI
    int prefix = 0;
#pragma unroll
    for (int ww = 0; ww < 4; ++ww) if (ww < w) prefix += wsumI[ww];
    const int cnt = wsumI[0] + wsumI[1] + wsumI[2] + wsumI[3];

    // ---- B3: place matching indices (deterministic order) ----
    int pos = prefix + v - cnt_t;
    for (int r = 0; r < rpt; ++r) {
        if ((mmask >> r) & 1) list[pos++] = base + r * 256 + tid;
    }

    // ---- C: center norms from LDS (wave w: rows 4w..4w+3) ----
    {
        float cc[4] = {0.f, 0.f, 0.f, 0.f};
#pragma unroll
        for (int kk = 0; kk < 4; ++kk) {
#pragma unroll
            for (int j = 0; j < 4; ++j) {
                const float4 t = *reinterpret_cast<const float4*>(
                    &cLDS[(4 * w + kk) * D + j * 256 + lane * 4]);
                cc[kk] += t.x * t.x + t.y * t.y + t.z * t.z + t.w * t.w;
            }
        }
#pragma unroll
        for (int off = 32; off >= 1; off >>= 1) {
#pragma unroll
            for (int kk = 0; kk < 4; ++kk) cc[kk] += __shfl_xor(cc[kk], off, 64);
        }
        if (lane == 0) {
#pragma unroll
            for (int kk = 0; kk < 4; ++kk)
                cinvLDS[4 * w + kk] = 1.0f / sqrtf(cc[kk] + EPS);
        }
    }
    __syncthreads();   // list + cinv complete

    // cinv -> per-lane registers (LDS broadcast reads)
    float cinv_r[K];
#pragma unroll
    for (int k = 0; k < K; ++k) cinv_r[k] = cinvLDS[k];

    // ---- D: pair-of-samples loop, waves independent, no barriers ----
    float wacc = 0.0f;
    const int npairs = (cnt + 1) >> 1;
    for (int t = w; t < npairs; t += 4) {
        const int  i1v = 2 * t + 1;
        const bool v1  = (i1v < cnt);
        const int  s0  = list[2 * t];
        const int  s1  = v1 ? list[i1v] : s0;

        const float* xr0 = x + (size_t)s0 * D;
        const float* xr1 = x + (size_t)s1 * D;
        float4 xa[4], xb[4];
#pragma unroll
        for (int j = 0; j < 4; ++j) {
            xa[j] = *reinterpret_cast<const float4*>(xr0 + j * 256 + lane * 4);
            xb[j] = *reinterpret_cast<const float4*>(xr1 + j * 256 + lane * 4);
        }

        float aa[K], ab[K];
#pragma unroll
        for (int k = 0; k < K; ++k) { aa[k] = 0.f; ab[k] = 0.f; }
        float xxa = 0.f, xxb = 0.f;
#pragma unroll
        for (int j = 0; j < 4; ++j) {
            xxa += xa[j].x * xa[j].x + xa[j].y * xa[j].y +
                   xa[j].z * xa[j].z + xa[j].w * xa[j].w;
            xxb += xb[j].x * xb[j].x + xb[j].y * xb[j].y +
                   xb[j].z * xb[j].z + xb[j].w * xb[j].w;
#pragma unroll
            for (int k = 0; k < K; ++k) {
                const float4 ck = *reinterpret_cast<const float4*>(
                    &cLDS[k * D + j * 256 + lane * 4]);
                aa[k] += ck.x * xa[j].x + ck.y * xa[j].y +
                         ck.z * xa[j].z + ck.w * xa[j].w;
                ab[k] += ck.x * xb[j].x + ck.y * xb[j].y +
                         ck.z * xb[j].z + ck.w * xb[j].w;
            }
        }

        // butterfly-reduce all 34 accumulators (independent -> 6-deep chain)
#pragma unroll
        for (int off = 32; off >= 1; off >>= 1) {
#pragma unroll
            for (int k = 0; k < K; ++k) {
                aa[k] += __shfl_xor(aa[k], off, 64);
                ab[k] += __shfl_xor(ab[k], off, 64);
            }
            xxa += __shfl_xor(xxa, off, 64);
            xxb += __shfl_xor(xxb, off, 64);
        }

        if (lane == 0) {
            {
                const float n0 = 1.0f / sqrtf(xxa + EPS);
                float sd = 0.f, sd2 = 0.f;
#pragma unroll
                for (int k = 0; k < K; ++k) {
                    const float dk = 1.0f - aa[k] * n0 * cinv_r[k];
                    sd  += dk;
                    sd2 += dk * dk;
                }
                wacc += sd - sd2 / sd;
            }
            if (v1) {
                const float n1 = 1.0f / sqrtf(xxb + EPS);
                float sd = 0.f, sd2 = 0.f;
#pragma unroll
                for (int k = 0; k < K; ++k) {
                    const float dk = 1.0f - ab[k] * n1 * cinv_r[k];
                    sd  += dk;
                    sd2 += dk * dk;
                }
                wacc += sd - sd2 / sd;
            }
        }
    }

    // ---- E: 4-wave combine + single atomic ----
    if (lane == 0) wpart[w] = wacc;
    __syncthreads();
    if (tid == 0) {
        const float bsum = (wpart[0] + wpart[1]) + (wpart[2] + wpart[3]);
        atomicAdd(out, bsum * inv_B);
    }
}

// ---------------------------------------------------------------------------
extern "C" void kernel_launch(void* const* d_in, const int* in_sizes, int n_in,
                              void* d_out, int out_size, void* d_ws, size_t ws_size,
                              hipStream_t stream) {
    const float* x       = (const float*)d_in[0];
    const int*   labels  = (const int*)d_in[1];
    const float* centers = (const float*)d_in[2];

    const int B = in_sizes[1];              // 8192
    const int C = in_sizes[2] / (K * D);    // 90
    const int nblocks = C * NS;             // 720

    float* out = (float*)d_out;

    // Zero the (poisoned) scalar output; graph-capturable memset node.
    hipMemsetAsync(out, 0, sizeof(float), stream);

    cosine_loss_fused<<<nblocks, 256, 0, stream>>>(
        x, labels, centers, out, B, C, 1.0f / (float)B);
}

// Round 9
// 125.618 us; speedup vs baseline: 2.0565x; 2.0565x over previous
//
#include <hip/hip_runtime.h>

#define EPS 1e-12f

constexpr int D       = 1024;  // feature dim
constexpr int K       = 16;    // centers per class
constexpr int NS      = 8;     // index-range slices per class
constexpr int LISTCAP = 1024;  // = SLICE (worst-case match count)

// ---------------------------------------------------------------------------
// Fused kernel. Block (c, sl) = (bid % C, bid / C):
//   A: stage class c's 16 center rows (64 KB) into LDS (deterministic
//      residency — round-6 lesson: register-resident centers get demoted).
//   B: scan labels[sl*SLICE ..), build LDS match list (shfl_up scan).
//   C: center norms from LDS -> cinvLDS -> per-lane registers.
//   D: sample loop — ONE sample per wave per iteration (round-7 lesson:
//      pairs spilled, WRITE_SIZE 230 MB). Live set ~80 VGPRs: xf[4] +
//      1-deep prefetch xn[4] + acc[17] + cinv_r[16]. 64 ds_read_b128 each
//      feeding 4 FMAs; 17-value butterfly; lane-0 epilogue; no barriers.
//   E: 4-wave combine, one atomicAdd (out pre-zeroed by memset node).
// ---------------------------------------------------------------------------
__global__ __launch_bounds__(256) void cosine_loss_fused(
    const float* __restrict__ x, const int* __restrict__ labels,
    const float* __restrict__ centers, float* __restrict__ out,
    int B, int C, float inv_B) {
    const int bid  = blockIdx.x;
    const int c    = bid % C;
    const int sl   = bid / C;
    const int tid  = threadIdx.x;
    const int w    = tid >> 6;
    const int lane = tid & 63;

    __shared__ float cLDS[K * D];      // 64 KB: class c's centers
    __shared__ int   list[LISTCAP];    // 4 KB: matching sample indices
    __shared__ int   wsumI[4];
    __shared__ float cinvLDS[K];
    __shared__ float wpart[4];

    const int SLICE = (B + NS - 1) / NS;       // 1024
    const int base  = sl * SLICE;
    const int lim   = min(SLICE, B - base);
    const int rpt   = (SLICE + 255) >> 8;      // 4

    // ---- A: stage centers -> LDS (coalesced float4, 16 iters/thread) ----
    {
        const float* csrc = centers + (size_t)c * (K * D);
#pragma unroll
        for (int i = 0; i < (K * D) / (256 * 4); ++i) {
            const int off = (i * 256 + tid) * 4;
            const float4 t = *reinterpret_cast<const float4*>(csrc + off);
            *reinterpret_cast<float4*>(&cLDS[off]) = t;
        }
    }

    // ---- B1: per-thread match mask over the slice (coalesced) ----
    int mmask = 0, cnt_t = 0;
    for (int r = 0; r < rpt; ++r) {
        const int idx = r * 256 + tid;
        if (idx < lim && labels[base + idx] == c) { mmask |= 1 << r; ++cnt_t; }
    }

    // ---- B2: intra-wave inclusive scan + cross-wave prefix ----
    int v = cnt_t;
#pragma unroll
    for (int off = 1; off < 64; off <<= 1) {
        const int u = __shfl_up(v, off, 64);
        if (lane >= off) v += u;
    }
    if (lane == 63) wsumI[w] = v;
    __syncthreads();   // covers staging writes + wsumI
    int prefix = 0;
#pragma unroll
    for (int ww = 0; ww < 4; ++ww) if (ww < w) prefix += wsumI[ww];
    const int cnt = wsumI[0] + wsumI[1] + wsumI[2] + wsumI[3];

    // ---- B3: place matching indices (deterministic order) ----
    int pos = prefix + v - cnt_t;
    for (int r = 0; r < rpt; ++r) {
        if ((mmask >> r) & 1) list[pos++] = base + r * 256 + tid;
    }

    // ---- C: center norms from LDS (wave w: rows 4w..4w+3) ----
    {
        float cc[4] = {0.f, 0.f, 0.f, 0.f};
#pragma unroll
        for (int kk = 0; kk < 4; ++kk) {
#pragma unroll
            for (int j = 0; j < 4; ++j) {
                const float4 t = *reinterpret_cast<const float4*>(
                    &cLDS[(4 * w + kk) * D + j * 256 + lane * 4]);
                cc[kk] += t.x * t.x + t.y * t.y + t.z * t.z + t.w * t.w;
            }
        }
#pragma unroll
        for (int off = 32; off >= 1; off >>= 1) {
#pragma unroll
            for (int kk = 0; kk < 4; ++kk) cc[kk] += __shfl_xor(cc[kk], off, 64);
        }
        if (lane == 0) {
#pragma unroll
            for (int kk = 0; kk < 4; ++kk)
                cinvLDS[4 * w + kk] = 1.0f / sqrtf(cc[kk] + EPS);
        }
    }
    __syncthreads();   // list + cinv complete

    // cinv -> per-lane registers (broadcast LDS reads, 16 regs)
    float cinv_r[K];
#pragma unroll
    for (int k = 0; k < K; ++k) cinv_r[k] = cinvLDS[k];

    // ---- D: one sample per wave per iteration, 1-deep prefetch ----
    float wacc = 0.0f;
    float4 xf[4];
    if (w < cnt) {
        const float* xr = x + (size_t)list[w] * D;
#pragma unroll
        for (int j = 0; j < 4; ++j)
            xf[j] = *reinterpret_cast<const float4*>(xr + j * 256 + lane * 4);
    }
    for (int si = w; si < cnt; si += 4) {
        float4 xn[4];
        const int sn = si + 4;
        if (sn < cnt) {
            const float* xr = x + (size_t)list[sn] * D;
#pragma unroll
            for (int j = 0; j < 4; ++j)
                xn[j] = *reinterpret_cast<const float4*>(xr + j * 256 + lane * 4);
        }

        float acc[K];
#pragma unroll
        for (int k = 0; k < K; ++k) acc[k] = 0.f;
        float xx = 0.f;
#pragma unroll
        for (int j = 0; j < 4; ++j) {
            xx += xf[j].x * xf[j].x + xf[j].y * xf[j].y +
                  xf[j].z * xf[j].z + xf[j].w * xf[j].w;
#pragma unroll
            for (int k = 0; k < K; ++k) {
                const float4 ck = *reinterpret_cast<const float4*>(
                    &cLDS[k * D + j * 256 + lane * 4]);
                acc[k] += ck.x * xf[j].x + ck.y * xf[j].y +
                          ck.z * xf[j].z + ck.w * xf[j].w;
            }
        }

        // butterfly-reduce 17 accumulators (independent chains)
#pragma unroll
        for (int off = 32; off >= 1; off >>= 1) {
#pragma unroll
            for (int k = 0; k < K; ++k) acc[k] += __shfl_xor(acc[k], off, 64);
            xx += __shfl_xor(xx, off, 64);
        }

        if (lane == 0) {
            const float n0 = 1.0f / sqrtf(xx + EPS);
            float sd = 0.f, sd2 = 0.f;
#pragma unroll
            for (int k = 0; k < K; ++k) {
                const float dk = 1.0f - acc[k] * n0 * cinv_r[k];
                sd  += dk;
                sd2 += dk * dk;
            }
            wacc += sd - sd2 / sd;
        }

        if (sn < cnt) {
#pragma unroll
            for (int j = 0; j < 4; ++j) xf[j] = xn[j];
        }
    }

    // ---- E: 4-wave combine + single atomic ----
    if (lane == 0) wpart[w] = wacc;
    __syncthreads();
    if (tid == 0) {
        const float bsum = (wpart[0] + wpart[1]) + (wpart[2] + wpart[3]);
        atomicAdd(out, bsum * inv_B);
    }
}

// ---------------------------------------------------------------------------
extern "C" void kernel_launch(void* const* d_in, const int* in_sizes, int n_in,
                              void* d_out, int out_size, void* d_ws, size_t ws_size,
                              hipStream_t stream) {
    const float* x       = (const float*)d_in[0];
    const int*   labels  = (const int*)d_in[1];
    const float* centers = (const float*)d_in[2];

    const int B = in_sizes[1];              // 8192
    const int C = in_sizes[2] / (K * D);    // 90
    const int nblocks = C * NS;             // 720

    float* out = (float*)d_out;

    // Zero the (poisoned) scalar output; graph-capturable memset node.
    hipMemsetAsync(out, 0, sizeof(float), stream);

    cosine_loss_fused<<<nblocks, 256, 0, stream>>>(
        x, labels, centers, out, B, C, 1.0f / (float)B);
}

// Round 10
// 93.058 us; speedup vs baseline: 2.7761x; 1.3499x over previous
//
#include <hip/hip_runtime.h>

#define EPS 1e-12f

constexpr int D       = 1024;  // feature dim
constexpr int K       = 16;    // centers per class
constexpr int NS      = 8;     // index-range slices per class
constexpr int LISTCAP = 1024;  // = SLICE (worst-case match count)
constexpr int CROWP   = D + 8; // padded LDS center row stride (shorts) -> 2-way conflict only

typedef __attribute__((ext_vector_type(8))) short  short8v;  // 8 bf16 (4 VGPR)
typedef __attribute__((ext_vector_type(4))) float  float4v;  // MFMA C/D

// fp32 -> bf16 with round-to-nearest-even (bit math, no API ambiguity)
__device__ __forceinline__ ushort f2bf(float f) {
    uint u = __float_as_uint(f);
    u += 0x7FFFu + ((u >> 16) & 1u);
    return (ushort)(u >> 16);
}

// ---------------------------------------------------------------------------
// Block (c, sl) = (bid % C, bid / C):
//   A: stage class c's centers as bf16 into LDS (wave w: rows 4w..4w+3),
//      fp32 norms computed during staging -> cinvLDS.
//   B: label scan -> LDS match list (as round 9, proven).
//   C: per 16-sample tile: 4 waves split K (wave w: d in [256w,256w+256),
//      8 MFMAs). A-frags converted on-the-fly from coalesced fp32 x loads
//      (x read once; per-(row,kt) the wave covers contiguous 128 B).
//      B-frags are ds_read_b128 from padded LDS. Partial accs + xx combined
//      via 5 KB LDS; wave 0 does a 4-step, 8-value epilogue butterfly.
//   D: one atomicAdd per block (out pre-zeroed by memset node).
// MFMA layout note: A and B use the IDENTICAL (lane-group g, j) -> k source
// mapping (elements g*8+j of the K=32 window), so any HW k-permutation
// cancels in the dot product. C/D mapping col=lane&15, row=(lane>>4)*4+q is
// the hardware-verified one.
// ---------------------------------------------------------------------------
__global__ __launch_bounds__(256) void cosine_loss_mfma(
    const float* __restrict__ x, const int* __restrict__ labels,
    const float* __restrict__ centers, float* __restrict__ out,
    int B, int C, float inv_B) {
    const int bid  = blockIdx.x;
    const int c    = bid % C;
    const int sl   = bid / C;
    const int tid  = threadIdx.x;
    const int w    = tid >> 6;
    const int lane = tid & 63;

    __shared__ ushort  cbLDS[K * CROWP];   // 33 KB bf16 centers (padded rows)
    __shared__ int     list[LISTCAP];      // 4 KB
    __shared__ int     wsumI[4];
    __shared__ float   cinvLDS[K];
    __shared__ float4v paccLDS[4][64];     // 4 KB partial dot tiles
    __shared__ float   xxLDS[4][64];       // 1 KB partial xx
    __shared__ float   xxrow[16];

    const int SLICE = (B + NS - 1) / NS;   // 1024
    const int base  = sl * SLICE;
    const int lim   = min(SLICE, B - base);
    const int rpt   = (SLICE + 255) >> 8;  // 4

    // ---- A: stage centers fp32 -> bf16 LDS + fp32 norms ----
#pragma unroll
    for (int rr = 0; rr < 4; ++rr) {
        const int r = 4 * w + rr;
        const float* crow = centers + (size_t)(c * K + r) * D;
        float cc = 0.f;
#pragma unroll
        for (int j = 0; j < 4; ++j) {
            const float4 v = *reinterpret_cast<const float4*>(crow + j * 256 + lane * 4);
            cc += v.x * v.x + v.y * v.y + v.z * v.z + v.w * v.w;
            uint2 p;
            p.x = (uint)f2bf(v.x) | ((uint)f2bf(v.y) << 16);
            p.y = (uint)f2bf(v.z) | ((uint)f2bf(v.w) << 16);
            *reinterpret_cast<uint2*>(&cbLDS[r * CROWP + j * 256 + lane * 4]) = p;
        }
#pragma unroll
        for (int off = 32; off >= 1; off >>= 1) cc += __shfl_xor(cc, off, 64);
        if (lane == 0) cinvLDS[r] = 1.0f / sqrtf(cc + EPS);
    }

    // ---- B1: per-thread match mask over the slice (coalesced) ----
    int mmask = 0, cnt_t = 0;
    for (int r = 0; r < rpt; ++r) {
        const int idx = r * 256 + tid;
        if (idx < lim && labels[base + idx] == c) { mmask |= 1 << r; ++cnt_t; }
    }

    // ---- B2: intra-wave inclusive scan + cross-wave prefix ----
    int vs = cnt_t;
#pragma unroll
    for (int off = 1; off < 64; off <<= 1) {
        const int u = __shfl_up(vs, off, 64);
        if (lane >= off) vs += u;
    }
    if (lane == 63) wsumI[w] = vs;
    __syncthreads();   // staging writes + wsumI visible
    int prefix = 0;
#pragma unroll
    for (int ww = 0; ww < 4; ++ww) if (ww < w) prefix += wsumI[ww];
    const int cnt = wsumI[0] + wsumI[1] + wsumI[2] + wsumI[3];

    // ---- B3: place matching indices ----
    int pos = prefix + vs - cnt_t;
    for (int r = 0; r < rpt; ++r) {
        if ((mmask >> r) & 1) list[pos++] = base + r * 256 + tid;
    }
    __syncthreads();   // list complete

    // ---- C: MFMA tile loop ----
    const int r16 = lane & 15;   // A row / B col owned by this lane
    const int g   = lane >> 4;   // k-group within the K=32 window
    float wacc = 0.f;

    for (int tb = 0; tb < cnt; tb += 16) {
        const int rown = tb + r16;
        const int sidx = list[rown < cnt ? rown : cnt - 1];  // clamp padding
        const float* xrow = x + (size_t)sidx * D;

        float4v acc = (float4v){0.f, 0.f, 0.f, 0.f};
        float xxp = 0.f;
#pragma unroll
        for (int kk = 0; kk < 8; ++kk) {
            const int kbase = (w * 8 + kk) * 32 + g * 8;   // element offset in row
            const float4 xa = *reinterpret_cast<const float4*>(xrow + kbase);
            const float4 xb = *reinterpret_cast<const float4*>(xrow + kbase + 4);
            xxp += xa.x * xa.x + xa.y * xa.y + xa.z * xa.z + xa.w * xa.w +
                   xb.x * xb.x + xb.y * xb.y + xb.z * xb.z + xb.w * xb.w;
            short8v af;
            af[0] = (short)f2bf(xa.x); af[1] = (short)f2bf(xa.y);
            af[2] = (short)f2bf(xa.z); af[3] = (short)f2bf(xa.w);
            af[4] = (short)f2bf(xb.x); af[5] = (short)f2bf(xb.y);
            af[6] = (short)f2bf(xb.z); af[7] = (short)f2bf(xb.w);
            const short8v bf = *reinterpret_cast<const short8v*>(
                &cbLDS[r16 * CROWP + kbase]);
            acc = __builtin_amdgcn_mfma_f32_16x16x32_bf16(af, bf, acc, 0, 0, 0);
        }
        paccLDS[w][lane] = acc;
        xxLDS[w][lane]   = xxp;
        __syncthreads();

        if (w == 0) {
            const float4v tot = paccLDS[0][lane] + paccLDS[1][lane] +
                                paccLDS[2][lane] + paccLDS[3][lane];
            if (lane < 16) {
                float s = 0.f;
#pragma unroll
                for (int ww = 0; ww < 4; ++ww)
#pragma unroll
                    for (int gg = 0; gg < 4; ++gg)
                        s += xxLDS[ww][lane + 16 * gg];
                xxrow[lane] = 1.0f / sqrtf(s + EPS);
            }
            // same-wave LDS RAW (in-order DS queue) — no barrier needed
            const float cv = cinvLDS[r16];
            float sd[4], sd2[4];
#pragma unroll
            for (int q = 0; q < 4; ++q) {
                const float dk = 1.0f - tot[q] * xxrow[g * 4 + q] * cv;
                sd[q] = dk;  sd2[q] = dk * dk;
            }
#pragma unroll
            for (int off = 1; off < 16; off <<= 1) {
#pragma unroll
                for (int q = 0; q < 4; ++q) {
                    sd[q]  += __shfl_xor(sd[q],  off, 64);
                    sd2[q] += __shfl_xor(sd2[q], off, 64);
                }
            }
            if (r16 == 0) {
#pragma unroll
                for (int q = 0; q < 4; ++q) {
                    const int row = g * 4 + q;
                    if (tb + row < cnt) wacc += sd[q] - sd2[q] / sd[q];
                }
            }
        }
        __syncthreads();   // pacc/xx reusable next tile
    }

    // ---- D: combine wave-0 lane partials (lanes 0/16/32/48) + atomic ----
    if (w == 0) {
        wacc += __shfl_xor(wacc, 16, 64);
        wacc += __shfl_xor(wacc, 32, 64);
        if (lane == 0) atomicAdd(out, wacc * inv_B);
    }
}

// ---------------------------------------------------------------------------
extern "C" void kernel_launch(void* const* d_in, const int* in_sizes, int n_in,
                              void* d_out, int out_size, void* d_ws, size_t ws_size,
                              hipStream_t stream) {
    const float* x       = (const float*)d_in[0];
    const int*   labels  = (const int*)d_in[1];
    const float* centers = (const float*)d_in[2];

    const int B = in_sizes[1];              // 8192
    const int C = in_sizes[2] / (K * D);    // 90
    const int nblocks = C * NS;             // 720

    float* out = (float*)d_out;

    // Zero the (poisoned) scalar output; graph-capturable memset node.
    hipMemsetAsync(out, 0, sizeof(float), stream);

    cosine_loss_mfma<<<nblocks, 256, 0, stream>>>(
        x, labels, centers, out, B, C, 1.0f / (float)B);
}